// Round 5
// baseline (339.679 us; speedup 1.0000x reference)
//
#include <hip/hip_runtime.h>
#include <math.h>

typedef float f32x4 __attribute__((ext_vector_type(4)));
typedef int   i32x4 __attribute__((ext_vector_type(4)));
typedef int   i32x8 __attribute__((ext_vector_type(8)));
typedef float f32x2 __attribute__((ext_vector_type(2)));

#define MTOT 16384
#define HALF 8192
#define KDIM 256                  /* bytes per row in fp8 Z */
#define BM 256                    /* tile edge */
#define NB (MTOT / BM)            /* 64 block-rows */
#define NBLK (NB * (NB + 1) / 2)  /* 2080 upper-triangle tiles */
#define NBLOCKS 256               /* persistent: 1 block per CU */
#define TPX (NBLK / 8)            /* 260 tiles per XCD */

#define GLDS16(g, l) __builtin_amdgcn_global_load_lds(                      \
    (const __attribute__((address_space(1))) void*)(g),                     \
    (__attribute__((address_space(3))) void*)(l), 16, 0, 0)

/* raw barrier: does NOT drain vmcnt */
#define BAR() do { asm volatile("" ::: "memory");                           \
  __builtin_amdgcn_s_barrier(); asm volatile("" ::: "memory"); } while (0)

// ---------------------------------------------------------------------------
// Pass 1: fp32 -> fp8 e4m3 via HW cvt_pk; row norms from the QUANTIZED
// values so the kernel-matrix diagonal cancels exactly. x2 stored
// pre-scaled by -0.5. Zero-inits the accumulator + completion counter.
// ---------------------------------------------------------------------------
__global__ __launch_bounds__(256) void convert_kernel(
    const float* __restrict__ Nmat, const float* __restrict__ Rmat,
    unsigned int* __restrict__ Z, float* __restrict__ x2,
    float* __restrict__ accum, unsigned int* __restrict__ counter) {
  if (blockIdx.x == 0 && threadIdx.x == 0) { *accum = 0.f; *counter = 0u; }
  const int lane = threadIdx.x & 63;
  const int wv = threadIdx.x >> 6;
  const int row = blockIdx.x * 4 + wv;          // 0..16383
  const float* src = (row < HALF) ? (Nmat + (size_t)row * KDIM)
                                  : (Rmat + (size_t)(row - HALF) * KDIM);
  float4 v = *(const float4*)(src + lane * 4);
  int pk = __builtin_amdgcn_cvt_pk_fp8_f32(v.x, v.y, 0, false);
  pk = __builtin_amdgcn_cvt_pk_fp8_f32(v.z, v.w, pk, true);
  Z[(size_t)row * (KDIM / 4) + lane] = (unsigned int)pk;
  f32x2 d01 = __builtin_amdgcn_cvt_pk_f32_fp8(pk, false);
  f32x2 d23 = __builtin_amdgcn_cvt_pk_f32_fp8(pk, true);
  float sq = d01[0] * d01[0] + d01[1] * d01[1] + d23[0] * d23[0] + d23[1] * d23[1];
  #pragma unroll
  for (int off = 32; off; off >>= 1) sq += __shfl_down(sq, off);
  if (lane == 0) x2[row] = -0.5f * sq;
}

__device__ __forceinline__ void decode_tile(int t, int& bm, int& bn) {
  const int u = NBLK - 1 - t;
  int rr = (int)((sqrtf(8.0f * (float)u + 1.0f) - 1.0f) * 0.5f);
  while (rr * (rr + 1) / 2 > u) --rr;
  while ((rr + 1) * (rr + 2) / 2 <= u) ++rr;
  bm = NB - 1 - rr;
  bn = bm + (t - (bm * NB - bm * (bm - 1) / 2));
}

// ---------------------------------------------------------------------------
// Pass 2. Structural diagnosis of rounds 0-4: elapsed == LDS-pipe time, not
// MFMA time. Per 64KB slab the old layout did 192 ds_read_b128 (~2300cy) +
// 512cy GLDS writes vs 2211cy of MFMA -> LDS-bound at every schedule.
//
// Fix: B never touches LDS. Each wave's B-fragment (64 cols x 128 K-bytes)
// is wave-private, so it loads global->registers (8 dwordx4/slab, double-
// buffered bfA/bfB, L2-resident). LDS now holds only A (2 x 32KB dbuf) and
// the FULL x2 array (64KB, staged once at prologue -> ACCINIT is ds_read
// only, zero steady-state vmem). New per-slab budget: LDS ~1800cy,
// L2 96KB ~1715cy, MFMA 2211cy -> MFMA-bound.
//
// Steady state per tile s (even slab -> buf0/bfA, odd -> buf1/bfB):
//   wait vmcnt(12); BAR; COMPUTE; LOADB(next, ->same reg buf); BAR;
//   STAGEA(next, ->same LDS buf)
// FIFO per wave is uniform 12 outstanding at each half-top (A[4]+B[8]+A[4]
// minus retired 4+8); prefetch distance 2 slabs for both streams; nothing
// waits vmcnt(0) until the final slab. Compiler-inserted waits for the
// B-register uses only cover ops OLDER than our manual wait -> no drain.
//
// A LDS swizzle (verified): slot s of row r holds chunk s^(r&7); b128
// fragment reads conflict-free.
// ---------------------------------------------------------------------------
__global__ __launch_bounds__(512, 2) void mmd_gemm(
    const unsigned char* __restrict__ Z, const float* __restrict__ x2,
    float* __restrict__ accum, unsigned int* __restrict__ counter,
    float* __restrict__ out) {
  __shared__ __align__(16) unsigned char As[2 * 32768];  // A K-slab dbuf
  __shared__ __align__(16) float x2l[MTOT];              // full -x2/2, 64 KB
  __shared__ __align__(16) float wsred[8];

  const int tid  = threadIdx.x;
  const int lane = tid & 63;
  const int wid  = tid >> 6;       // 0..7
  const int wm   = wid >> 2;       // wave row (0..1): 128 output rows
  const int wn   = wid & 3;        // wave col (0..3): 64 output cols

  // A staging geometry (swizzle key == row&7 == lane>>3)
  const int lr = lane >> 3;
  const int ls = lane & 7;
  const int cofs = lr * KDIM + ((ls ^ lr) << 4);

  // fragment geometry
  const int fr = lane & 15;
  const int fq = lane >> 4;
  const int key = fr & 7;
  const int slotL = ((2 * fq) ^ key) * 16;
  const int slotH = ((2 * fq + 1) ^ key) * 16;

  const int xcd = blockIdx.x & 7;
  const int lb  = blockIdx.x >> 3;                    // 0..31 within XCD
  const int niter = (lb < (TPX & 31)) ? (TPX / 32 + 1) : (TPX / 32); // 9 or 8

  f32x4 acc[8][4];
  i32x4 bfA[8], bfB[8];
  float running = 0.f;

  auto STAGEA = [&](int bmv, int h, int buf) {     // 4 GLDS16 / wave
    const unsigned char* Ab = Z + (size_t)bmv * (BM * KDIM) + h * 128 + cofs;
    unsigned char* Ad = As + buf * 32768;
    #pragma unroll
    for (int tt = 0; tt < 4; ++tt) {
      int i = wid * 4 + tt;                        // wave-uniform id, 8 rows each
      GLDS16(Ab + i * 2048, Ad + i * 1024);
    }
  };

  auto LOADB = [&](int bnv, int h, i32x4* dst) {   // 8 global dwordx4 / wave
    const unsigned char* base = Z + (size_t)bnv * (BM * KDIM)
                                  + (size_t)(wn * 64 + fr) * KDIM + h * 128 + fq * 32;
    #pragma unroll
    for (int tn = 0; tn < 4; ++tn) {
      dst[2 * tn]     = *(const i32x4*)(base + (size_t)tn * 16 * KDIM);
      dst[2 * tn + 1] = *(const i32x4*)(base + (size_t)tn * 16 * KDIM + 16);
    }
  };

  auto ACCINIT = [&](int bmv, int bnv) {           // LDS-only (lgkmcnt)
    float xch[4];
    #pragma unroll
    for (int tn = 0; tn < 4; ++tn)
      xch[tn] = x2l[bnv * BM + wn * 64 + tn * 16 + fr];
    #pragma unroll
    for (int tm = 0; tm < 8; ++tm) {
      f32x4 xr = *(const f32x4*)&x2l[bmv * BM + wm * 128 + tm * 16 + fq * 4];
      #pragma unroll
      for (int tn = 0; tn < 4; ++tn)
        #pragma unroll
        for (int v = 0; v < 4; ++v)
          acc[tm][tn][v] = xr[v] + xch[tn];
    }
  };

  auto COMPUTE = [&](const unsigned char* A_s, const i32x4* bfr) {
    i32x8 bf[4];
    #pragma unroll
    for (int tn = 0; tn < 4; ++tn)
      bf[tn] = __builtin_shufflevector(bfr[2 * tn], bfr[2 * tn + 1],
                                       0, 1, 2, 3, 4, 5, 6, 7);
    #pragma unroll
    for (int tm = 0; tm < 8; ++tm) {
      int row = wm * 128 + tm * 16 + fr;
      i32x4 lo = *(const i32x4*)(A_s + row * 128 + slotL);
      i32x4 hi = *(const i32x4*)(A_s + row * 128 + slotH);
      i32x8 af = __builtin_shufflevector(lo, hi, 0, 1, 2, 3, 4, 5, 6, 7);
      #pragma unroll
      for (int tn = 0; tn < 4; ++tn)
        acc[tm][tn] = __builtin_amdgcn_mfma_scale_f32_16x16x128_f8f6f4(
            af, bf[tn], acc[tm][tn], 0, 0,
            0, 0x7F7F7F7F, 0, 0x7F7F7F7F);
    }
  };

  int cbm, cbn, nbm, nbn;
  decode_tile(xcd * TPX + lb, cbm, cbn);

  // ---- prologue. vmem issue order: x2[8], A0[4], B0[8], A1[4], B1[8] = 32
  #pragma unroll
  for (int t = 0; t < 8; ++t) {
    int i = wid * 8 + t;
    GLDS16((const unsigned char*)x2 + i * 1024 + (size_t)lane * 16,
           (unsigned char*)x2l + i * 1024);
  }
  STAGEA(cbm, 0, 0);
  LOADB(cbn, 0, bfA);
  STAGEA(cbm, 1, 1);
  LOADB(cbn, 1, bfB);
  asm volatile("s_waitcnt vmcnt(24)" ::: "memory");  // retire x2 stage only
  BAR();                                             // all waves' x2 in LDS
  ACCINIT(cbm, cbn);

  for (int s = 0; s < niter; ++s) {
    const bool haveNext = (s + 1 < niter);
    if (haveNext) decode_tile(xcd * TPX + lb + 32 * (s + 1), nbm, nbn);

    // ---- even slab: A buf0, B bfA
    asm volatile("s_waitcnt vmcnt(12)" ::: "memory");  // A(even)+B(even) landed
    BAR();
    COMPUTE(As, bfA);
    if (haveNext) LOADB(nbn, 0, bfA);    // bfA dead after COMPUTE
    BAR();                               // all waves done reading buf0
    if (haveNext) STAGEA(nbm, 0, 0);

    // ---- odd slab: A buf1, B bfB
    if (haveNext) asm volatile("s_waitcnt vmcnt(12)" ::: "memory");
    else          asm volatile("s_waitcnt vmcnt(0)"  ::: "memory");
    BAR();
    COMPUTE(As + 32768, bfB);
    if (haveNext) LOADB(nbn, 1, bfB);
    BAR();                               // all waves done reading buf1
    if (haveNext) STAGEA(nbm, 1, 1);

    // ---- tile (cbm,cbn) finished: acc = -d2/2
    float amax = -1e30f;
    #pragma unroll
    for (int tm = 0; tm < 8; ++tm)
      #pragma unroll
      for (int tn = 0; tn < 4; ++tn) {   // v_max3-friendly
        float m1 = fmaxf(fmaxf(acc[tm][tn][0], acc[tm][tn][1]), acc[tm][tn][2]);
        amax = fmaxf(fmaxf(amax, m1), acc[tm][tn][3]);
      }

    float partial = 0.f;
    if (__any(amax > -40.f)) {           // diagonal tiles + freak near-pairs
      #pragma unroll
      for (int tm = 0; tm < 8; ++tm)
        #pragma unroll
        for (int tn = 0; tn < 4; ++tn)
          #pragma unroll
          for (int v = 0; v < 4; ++v) {
            float a = fminf(acc[tm][tn][v], 0.f);   // clamp d2 >= 0
            partial += exp2f(a * 2.885390082f);     // exp(2a)
          }
    }
    float wgt = ((cbm < NB / 2) == (cbn < NB / 2)) ? 1.f : -1.f;
    if (cbm != cbn) wgt *= 2.f;          // off-diag: symmetry
    running += partial * wgt;

    if (haveNext) { ACCINIT(nbm, nbn); cbm = nbm; cbn = nbn; }
  }

  // ---- final reduce: one shfl cascade + one atomic per block
  #pragma unroll
  for (int off = 32; off; off >>= 1) running += __shfl_down(running, off);
  if (lane == 0) wsred[wid] = running;
  __syncthreads();
  if (tid == 0) {
    float bs = 0.f;
    #pragma unroll
    for (int w = 0; w < 8; ++w) bs += wsred[w];
    atomicAdd(accum, bs);
    __threadfence();                     // order adds before counter bump
    unsigned int old = atomicAdd(counter, 1u);
    if (old == NBLOCKS - 1) {            // last block: all adds L2-visible
      float tot = atomicAdd(accum, 0.f); // coherent RMW read
      float mmd = tot / ((float)HALF * (float)HALF);
      out[0] = sqrtf(fmaxf(mmd, 0.f));
    }
  }
}

extern "C" void kernel_launch(void* const* d_in, const int* in_sizes, int n_in,
                              void* d_out, int out_size, void* d_ws, size_t ws_size,
                              hipStream_t stream) {
  const float* Nmat = (const float*)d_in[0];
  const float* Rmat = (const float*)d_in[1];
  float* out = (float*)d_out;

  char* ws = (char*)d_ws;
  unsigned char* Z = (unsigned char*)ws;                       // 4 MiB
  float* x2        = (float*)(ws + (size_t)MTOT * KDIM);       // 64 KiB
  float* accum     = (float*)(ws + (size_t)MTOT * KDIM + (size_t)MTOT * 4);
  unsigned int* counter = (unsigned int*)(ws + (size_t)MTOT * KDIM + (size_t)MTOT * 4 + 4);

  convert_kernel<<<MTOT / 4, 256, 0, stream>>>(Nmat, Rmat, (unsigned int*)Z, x2,
                                               accum, counter);
  mmd_gemm<<<NBLOCKS, 512, 0, stream>>>(Z, x2, accum, counter, out);
}

// Round 6
// 290.543 us; speedup vs baseline: 1.1691x; 1.1691x over previous
//
#include <hip/hip_runtime.h>
#include <math.h>

typedef float f32x4 __attribute__((ext_vector_type(4)));
typedef int   i32x4 __attribute__((ext_vector_type(4)));
typedef int   i32x8 __attribute__((ext_vector_type(8)));
typedef float f32x2 __attribute__((ext_vector_type(2)));

#define MTOT 16384
#define HALF 8192
#define KDIM 256                  /* bytes per row in fp8 Z */
#define BM 128
#define NB (MTOT / BM)            /* 128 block-rows */
#define NBLK (NB * (NB + 1) / 2)  /* 8256 upper-triangle tiles */

#define GLDS16(g, l) __builtin_amdgcn_global_load_lds(                      \
    (const __attribute__((address_space(1))) void*)(g),                     \
    (__attribute__((address_space(3))) void*)(l), 16, 0, 0)

// ---------------------------------------------------------------------------
// Pass 1: fp32 -> fp8 e4m3 via HW cvt_pk; row norms from the QUANTIZED
// values so the kernel-matrix diagonal cancels exactly. x2 stored
// pre-scaled by -0.5. Zero-inits the accumulator + completion counter.
// ---------------------------------------------------------------------------
__global__ __launch_bounds__(256) void convert_kernel(
    const float* __restrict__ Nmat, const float* __restrict__ Rmat,
    unsigned int* __restrict__ Z, float* __restrict__ x2,
    float* __restrict__ accum, unsigned int* __restrict__ counter) {
  if (blockIdx.x == 0 && threadIdx.x == 0) { *accum = 0.f; *counter = 0u; }
  const int lane = threadIdx.x & 63;
  const int wv = threadIdx.x >> 6;
  const int row = blockIdx.x * 4 + wv;          // 0..16383
  const float* src = (row < HALF) ? (Nmat + (size_t)row * KDIM)
                                  : (Rmat + (size_t)(row - HALF) * KDIM);
  float4 v = *(const float4*)(src + lane * 4);
  int pk = __builtin_amdgcn_cvt_pk_fp8_f32(v.x, v.y, 0, false);
  pk = __builtin_amdgcn_cvt_pk_fp8_f32(v.z, v.w, pk, true);
  Z[(size_t)row * (KDIM / 4) + lane] = (unsigned int)pk;
  f32x2 d01 = __builtin_amdgcn_cvt_pk_f32_fp8(pk, false);
  f32x2 d23 = __builtin_amdgcn_cvt_pk_f32_fp8(pk, true);
  float sq = d01[0] * d01[0] + d01[1] * d01[1] + d23[0] * d23[0] + d23[1] * d23[1];
  #pragma unroll
  for (int off = 32; off; off >>= 1) sq += __shfl_down(sq, off);
  if (lane == 0) x2[row] = -0.5f * sq;
}

// ---------------------------------------------------------------------------
// Pass 2: upper-block-triangular S = Z Z^T, 128x128 tiles, dispatch-per-tile
// (the measured-best round-0 structure: 8256 blocks x 256 thr, 2 blocks/CU).
//
// Round-6 deltas vs round 0, each with one mechanism:
//  - K-SPLIT STAGING: round 0 staged all 64 KB then drained vmcnt(0) at one
//    barrier (~40% of block time exposed). Here: stage K-half-0 (32 KB) ->
//    sync -> ISSUE K-half-1 -> compute ks=0 (~1300 cy covers the 32 KB L2
//    fetch) -> sync (drains half-1, already landed) -> compute ks=1. LDS
//    stays 64 KB so 2 blocks/CU is preserved (cross-block overlap intact).
//  - XCD SWIZZLE (8256 = 8*1032, bijective): neighboring tiles of one bm
//    panel land on one XCD's L2; round-0 FETCH (17.5 MB ~ 4x Z) says panels
//    were re-fetched across XCDs.
//  - x2 consumed in EPILOGUE (loads issued after sync-1, drained for free
//    by sync-2): prologue drain covers only the 32 KB stage-0.
//  - fused finalize via accum+counter (rounds 4/5-verified): no 3rd kernel.
//  - s_setprio(1) around MFMA: independent blocks at staggered phases is
//    the regime where it measured positive.
//
// LDS layout per K-half (verified rounds 0/4/5): row r of a half holds its
// 8 16B-chunks at slot c ^ (r&7); staging lane l of instr i sources chunk
// (l&7)^(l>>3) of row i*8+(l>>3); b128 fragment reads conflict-free.
// Epilogue: a = s - (xi+xj)/2 = -d2/2; exp(-d2) == 0 in fp32 when a <= -40,
// proven per-wave via __any (exp path runs on ~128/8256 diagonal tiles).
// ---------------------------------------------------------------------------
__global__ __launch_bounds__(256, 2) void mmd_gemm(
    const unsigned char* __restrict__ Z, const float* __restrict__ x2,
    float* __restrict__ accum, unsigned int* __restrict__ counter,
    float* __restrict__ out) {
  // XCD-chunked tile id (bijective since 8256 % 8 == 0)
  const int t = (blockIdx.x & 7) * (NBLK / 8) + (blockIdx.x >> 3);
  const int u = NBLK - 1 - t;
  int rr = (int)((sqrtf(8.0f * (float)u + 1.0f) - 1.0f) * 0.5f);
  while (rr * (rr + 1) / 2 > u) --rr;
  while ((rr + 1) * (rr + 2) / 2 <= u) ++rr;
  const int bm = NB - 1 - rr;
  const int bn = bm + (t - (bm * NB - bm * (bm - 1) / 2));

  __shared__ __align__(16) unsigned char As[2][BM * 128];  // 2 K-halves, 16 KB each
  __shared__ __align__(16) unsigned char Bs[2][BM * 128];
  __shared__ __align__(16) float wsred[4];

  const int tid  = threadIdx.x;
  const int lane = tid & 63;
  const int wid  = tid >> 6;       // 0..3
  const int wm   = wid >> 1;       // wave row (0..1)
  const int wn   = wid & 1;        // wave col (0..1)

  // staging geometry (swizzle key == row&7 == lane>>3)
  const int lr = lane >> 3;
  const int ls = lane & 7;
  const int cofs = lr * KDIM + ((ls ^ lr) << 4);

  // fragment geometry
  const int fr = lane & 15;
  const int fq = lane >> 4;        // 0..3
  const int key = fr & 7;
  const int slotL = ((2 * fq) ^ key) * 16;
  const int slotH = ((2 * fq + 1) ^ key) * 16;

  const unsigned char* Abase = Z + (size_t)bm * BM * KDIM;
  const unsigned char* Bbase = Z + (size_t)bn * BM * KDIM;

  auto STAGE = [&](int h) {        // 8 GLDS16 / wave (A 4 + B 4)
    #pragma unroll
    for (int tt = 0; tt < 4; ++tt) {
      int i = wid * 4 + tt;        // wave-uniform; covers rows 8i..8i+7
      GLDS16(Abase + (size_t)i * 8 * KDIM + h * 128 + cofs, &As[h][i * 1024]);
      GLDS16(Bbase + (size_t)i * 8 * KDIM + h * 128 + cofs, &Bs[h][i * 1024]);
    }
  };

  f32x4 acc[4][4];
  #pragma unroll
  for (int tm = 0; tm < 4; ++tm)
    #pragma unroll
    for (int tn = 0; tn < 4; ++tn)
      #pragma unroll
      for (int v = 0; v < 4; ++v) acc[tm][tn][v] = 0.f;

  STAGE(0);                        // K-bytes [0,128)
  __syncthreads();                 // drains ONLY stage-0 (nothing else issued)
  STAGE(1);                        // K-bytes [128,256): lands under ks=0 MFMA

  // x2 (prescaled -0.5): consumed only in the epilogue; sync-2 drains these
  // together with stage-1, so they cost no extra stall.
  float xr[4][4];
  float xc[4];
  #pragma unroll
  for (int tm = 0; tm < 4; ++tm) {
    float4 v = *(const float4*)(x2 + bm * BM + wm * 64 + tm * 16 + fq * 4);
    xr[tm][0] = v.x; xr[tm][1] = v.y; xr[tm][2] = v.z; xr[tm][3] = v.w;
  }
  #pragma unroll
  for (int tn = 0; tn < 4; ++tn)
    xc[tn] = x2[bn * BM + wn * 64 + tn * 16 + fr];

  #pragma unroll
  for (int ks = 0; ks < 2; ++ks) {
    i32x8 bf[4];
    #pragma unroll
    for (int tn = 0; tn < 4; ++tn) {
      int row = wn * 64 + tn * 16 + fr;
      i32x4 lo = *(const i32x4*)(&Bs[ks][row * 128 + slotL]);
      i32x4 hi = *(const i32x4*)(&Bs[ks][row * 128 + slotH]);
      bf[tn] = __builtin_shufflevector(lo, hi, 0, 1, 2, 3, 4, 5, 6, 7);
    }
    __builtin_amdgcn_s_setprio(1);
    #pragma unroll
    for (int tm = 0; tm < 4; ++tm) {
      int row = wm * 64 + tm * 16 + fr;
      i32x4 lo = *(const i32x4*)(&As[ks][row * 128 + slotL]);
      i32x4 hi = *(const i32x4*)(&As[ks][row * 128 + slotH]);
      i32x8 af = __builtin_shufflevector(lo, hi, 0, 1, 2, 3, 4, 5, 6, 7);
      #pragma unroll
      for (int tn = 0; tn < 4; ++tn)
        acc[tm][tn] = __builtin_amdgcn_mfma_scale_f32_16x16x128_f8f6f4(
            af, bf[tn], acc[tm][tn], 0, 0,
            0, 0x7F7F7F7F, 0, 0x7F7F7F7F);
    }
    __builtin_amdgcn_s_setprio(0);
    if (ks == 0) __syncthreads();  // stage-1 resident (fetch covered by ks=0)
  }

  // ---- epilogue: a = acc - (xi+xj)/2 = -d2/2
  #pragma unroll
  for (int tm = 0; tm < 4; ++tm)
    #pragma unroll
    for (int tn = 0; tn < 4; ++tn)
      #pragma unroll
      for (int v = 0; v < 4; ++v)
        acc[tm][tn][v] += xr[tm][v] + xc[tn];

  float amax = -1e30f;
  #pragma unroll
  for (int tm = 0; tm < 4; ++tm)
    #pragma unroll
    for (int tn = 0; tn < 4; ++tn) {       // v_max3-friendly
      float m1 = fmaxf(fmaxf(acc[tm][tn][0], acc[tm][tn][1]), acc[tm][tn][2]);
      amax = fmaxf(fmaxf(amax, m1), acc[tm][tn][3]);
    }

  float partial = 0.f;
  if (__any(amax > -40.f)) {       // diagonal tiles + any freak near-pair
    #pragma unroll
    for (int tm = 0; tm < 4; ++tm)
      #pragma unroll
      for (int tn = 0; tn < 4; ++tn)
        #pragma unroll
        for (int v = 0; v < 4; ++v) {
          float a = fminf(acc[tm][tn][v], 0.f);   // clamp d2 >= 0
          partial += exp2f(a * 2.885390082f);     // exp(2a)
        }
  }

  #pragma unroll
  for (int off = 32; off; off >>= 1) partial += __shfl_down(partial, off);
  if (lane == 0) wsred[wid] = partial;
  __syncthreads();

  if (tid == 0) {
    float bs = wsred[0] + wsred[1] + wsred[2] + wsred[3];
    // Block weight: sign(N/R half); off-diag x2 (symmetry). Row 8192
    // boundary == block 64, so sign is block-uniform.
    float wgt = ((bm < NB / 2) == (bn < NB / 2)) ? 1.f : -1.f;
    if (bm != bn) wgt *= 2.f;
    atomicAdd(accum, bs * wgt);
    __threadfence();               // order accum-add before counter bump
    unsigned int old = atomicAdd(counter, 1u);
    if (old == NBLK - 1) {         // last block: all adds are L2-visible
      float tot = atomicAdd(accum, 0.f);   // coherent RMW read
      float mmd = tot / ((float)HALF * (float)HALF);
      out[0] = sqrtf(fmaxf(mmd, 0.f));
    }
  }
}

extern "C" void kernel_launch(void* const* d_in, const int* in_sizes, int n_in,
                              void* d_out, int out_size, void* d_ws, size_t ws_size,
                              hipStream_t stream) {
  const float* Nmat = (const float*)d_in[0];
  const float* Rmat = (const float*)d_in[1];
  float* out = (float*)d_out;

  char* ws = (char*)d_ws;
  unsigned char* Z = (unsigned char*)ws;                       // 4 MiB
  float* x2        = (float*)(ws + (size_t)MTOT * KDIM);       // 64 KiB
  float* accum     = (float*)(ws + (size_t)MTOT * KDIM + (size_t)MTOT * 4);
  unsigned int* counter = (unsigned int*)(ws + (size_t)MTOT * KDIM + (size_t)MTOT * 4 + 4);

  convert_kernel<<<MTOT / 4, 256, 0, stream>>>(Nmat, Rmat, (unsigned int*)Z, x2,
                                               accum, counter);
  mmd_gemm<<<NBLK, 256, 0, stream>>>(Z, x2, accum, counter, out);
}

// Round 7
// 125.555 us; speedup vs baseline: 2.7054x; 2.3141x over previous
//
#include <hip/hip_runtime.h>
#include <math.h>

typedef float f32x4 __attribute__((ext_vector_type(4)));
typedef int   i32x4 __attribute__((ext_vector_type(4)));
typedef int   i32x8 __attribute__((ext_vector_type(8)));
typedef float f32x2 __attribute__((ext_vector_type(2)));

#define MTOT 16384
#define HALF 8192
#define KDIM 256                  /* bytes per row in fp8 Z */
#define BM 128
#define NB (MTOT / BM)            /* 128 block-rows */
#define NBLK (NB * (NB + 1) / 2)  /* 8256 upper-triangle tiles */
#define NPART (NBLK * 4)          /* one partial per wave */

#define GLDS16(g, l) __builtin_amdgcn_global_load_lds(                      \
    (const __attribute__((address_space(1))) void*)(g),                     \
    (__attribute__((address_space(3))) void*)(l), 16, 0, 0)

// ---------------------------------------------------------------------------
// Pass 1: fp32 -> fp8 e4m3 via HW cvt_pk; row norms from the QUANTIZED
// values so the kernel-matrix diagonal cancels exactly. x2 stored
// pre-scaled by -0.5 (only ever consumed that way).
// ---------------------------------------------------------------------------
__global__ __launch_bounds__(256) void convert_kernel(
    const float* __restrict__ Nmat, const float* __restrict__ Rmat,
    unsigned int* __restrict__ Z, float* __restrict__ x2) {
  const int lane = threadIdx.x & 63;
  const int wv = threadIdx.x >> 6;
  const int row = blockIdx.x * 4 + wv;          // 0..16383
  const float* src = (row < HALF) ? (Nmat + (size_t)row * KDIM)
                                  : (Rmat + (size_t)(row - HALF) * KDIM);
  float4 v = *(const float4*)(src + lane * 4);
  int pk = __builtin_amdgcn_cvt_pk_fp8_f32(v.x, v.y, 0, false);
  pk = __builtin_amdgcn_cvt_pk_fp8_f32(v.z, v.w, pk, true);
  Z[(size_t)row * (KDIM / 4) + lane] = (unsigned int)pk;
  f32x2 d01 = __builtin_amdgcn_cvt_pk_f32_fp8(pk, false);
  f32x2 d23 = __builtin_amdgcn_cvt_pk_f32_fp8(pk, true);
  float sq = d01[0] * d01[0] + d01[1] * d01[1] + d23[0] * d23[0] + d23[1] * d23[1];
  #pragma unroll
  for (int off = 32; off; off >>= 1) sq += __shfl_down(sq, off);
  if (lane == 0) x2[row] = -0.5f * sq;
}

// ---------------------------------------------------------------------------
// Pass 2: upper-block-triangular S = Z Z^T, 128x128 tiles, dispatch-per-tile
// (round-0 structure: 8256 blocks x 256 thr, 2 blocks/CU, NO atomics --
// round 6's 5x regression was 8256 same-cacheline device atomics + fences
// in the fused finalize: everything idle, occupancy halved, ~200us of
// serialized coherence traffic. Partials array + finalize kernel restored.)
//
// Kept deltas vs round 0 (one mechanism each):
//  - K-SPLIT STAGING: round 0 staged 64 KB then drained vmcnt(0) at one
//    barrier (~40% of block time exposed). Here: STAGE(half-0, 32 KB) ->
//    x2 load + acc init (covers the drain, as in round 0) -> sync ->
//    issue STAGE(half-1) -> compute ks=0 (~550 cy covers the 32 KB L2
//    fetch) -> sync -> compute ks=1. LDS stays 64 KB -> 2 blocks/CU.
//  - XCD SWIZZLE (8256 = 8*1032, bijective): round 6 measured FETCH
//    17.5 -> 12.7 MB from this; cost ~zero.
//
// LDS layout per K-half (verified round 6: passed, same absmax): row r of
// half h holds its 8 16B-chunks at slot c ^ (r&7); staging instr i covers
// rows 8i..8i+7, lane l sources chunk (l&7)^(l>>3) of row i*8+(l>>3);
// b128 fragment reads hit all 32 banks.
//
// acc init = -(x2[i]+x2[j])/2 so acc ends as -d2/2; off-diagonal tiles
// prove exp==0 via 64-wide max + __any (exp runs on ~128/8256 tiles).
// ---------------------------------------------------------------------------
__global__ __launch_bounds__(256, 2) void mmd_gemm(
    const unsigned char* __restrict__ Z, const float* __restrict__ x2,
    float* __restrict__ partials) {
  // XCD-chunked tile id (bijective since 8256 % 8 == 0)
  const int t = (blockIdx.x & 7) * (NBLK / 8) + (blockIdx.x >> 3);
  const int u = NBLK - 1 - t;
  int rr = (int)((sqrtf(8.0f * (float)u + 1.0f) - 1.0f) * 0.5f);
  while (rr * (rr + 1) / 2 > u) --rr;
  while ((rr + 1) * (rr + 2) / 2 <= u) ++rr;
  const int bm = NB - 1 - rr;
  const int bn = bm + (t - (bm * NB - bm * (bm - 1) / 2));

  __shared__ __align__(16) unsigned char As[2][BM * 128];  // 2 K-halves, 16 KB each
  __shared__ __align__(16) unsigned char Bs[2][BM * 128];

  const int tid  = threadIdx.x;
  const int lane = tid & 63;
  const int wid  = tid >> 6;       // 0..3
  const int wm   = wid >> 1;       // wave row (0..1)
  const int wn   = wid & 1;        // wave col (0..1)

  // staging geometry (swizzle key == row&7 == lane>>3)
  const int lr = lane >> 3;
  const int ls = lane & 7;
  const int cofs = lr * KDIM + ((ls ^ lr) << 4);

  // fragment geometry
  const int fr = lane & 15;
  const int fq = lane >> 4;        // 0..3
  const int key = fr & 7;
  const int slotL = ((2 * fq) ^ key) * 16;
  const int slotH = ((2 * fq + 1) ^ key) * 16;

  const unsigned char* Abase = Z + (size_t)bm * BM * KDIM;
  const unsigned char* Bbase = Z + (size_t)bn * BM * KDIM;

  auto STAGE = [&](int h) {        // 8 GLDS16 / wave (A 4 + B 4)
    #pragma unroll
    for (int tt = 0; tt < 4; ++tt) {
      int i = wid * 4 + tt;        // wave-uniform; covers rows 8i..8i+7
      GLDS16(Abase + (size_t)i * 8 * KDIM + h * 128 + cofs, &As[h][i * 1024]);
      GLDS16(Bbase + (size_t)i * 8 * KDIM + h * 128 + cofs, &Bs[h][i * 1024]);
    }
  };

  STAGE(0);                        // K-bytes [0,128) in flight

  // x2 (prescaled -0.5) + acc init: covers the stage-0 drain (round-0
  // prologue pattern -- the x2 waits retire stage-0 alongside).
  float xch[4];
  #pragma unroll
  for (int tn = 0; tn < 4; ++tn)
    xch[tn] = x2[bn * BM + wn * 64 + tn * 16 + fr];

  f32x4 acc[4][4];
  #pragma unroll
  for (int tm = 0; tm < 4; ++tm) {
    float4 xr = *(const float4*)(x2 + bm * BM + wm * 64 + tm * 16 + fq * 4);
    #pragma unroll
    for (int tn = 0; tn < 4; ++tn) {
      acc[tm][tn][0] = xr.x + xch[tn];
      acc[tm][tn][1] = xr.y + xch[tn];
      acc[tm][tn][2] = xr.z + xch[tn];
      acc[tm][tn][3] = xr.w + xch[tn];
    }
  }

  __syncthreads();                 // stage-0 resident for all waves
  STAGE(1);                        // K-bytes [128,256): lands under ks=0 MFMA

  #pragma unroll
  for (int ks = 0; ks < 2; ++ks) {
    i32x8 bf[4];
    #pragma unroll
    for (int tn = 0; tn < 4; ++tn) {
      int row = wn * 64 + tn * 16 + fr;
      i32x4 lo = *(const i32x4*)(&Bs[ks][row * 128 + slotL]);
      i32x4 hi = *(const i32x4*)(&Bs[ks][row * 128 + slotH]);
      bf[tn] = __builtin_shufflevector(lo, hi, 0, 1, 2, 3, 4, 5, 6, 7);
    }
    #pragma unroll
    for (int tm = 0; tm < 4; ++tm) {
      int row = wm * 64 + tm * 16 + fr;
      i32x4 lo = *(const i32x4*)(&As[ks][row * 128 + slotL]);
      i32x4 hi = *(const i32x4*)(&As[ks][row * 128 + slotH]);
      i32x8 af = __builtin_shufflevector(lo, hi, 0, 1, 2, 3, 4, 5, 6, 7);
      #pragma unroll
      for (int tn = 0; tn < 4; ++tn)
        acc[tm][tn] = __builtin_amdgcn_mfma_scale_f32_16x16x128_f8f6f4(
            af, bf[tn], acc[tm][tn], 0, 0,
            0, 0x7F7F7F7F, 0, 0x7F7F7F7F);
    }
    if (ks == 0) __syncthreads();  // stage-1 resident (fetch covered by ks=0)
  }

  // ---- epilogue: acc = -d2/2; exp(-d2)==0 in fp32 whenever acc <= -40
  float amax = -1e30f;
  #pragma unroll
  for (int tm = 0; tm < 4; ++tm)
    #pragma unroll
    for (int tn = 0; tn < 4; ++tn) {       // v_max3-friendly
      float m1 = fmaxf(fmaxf(acc[tm][tn][0], acc[tm][tn][1]), acc[tm][tn][2]);
      amax = fmaxf(fmaxf(amax, m1), acc[tm][tn][3]);
    }

  float partial = 0.f;
  if (__any(amax > -40.f)) {       // diagonal tiles + any freak near-pair
    #pragma unroll
    for (int tm = 0; tm < 4; ++tm)
      #pragma unroll
      for (int tn = 0; tn < 4; ++tn)
        #pragma unroll
        for (int v = 0; v < 4; ++v) {
          float a = fminf(acc[tm][tn][v], 0.f);   // clamp d2 >= 0
          partial += exp2f(a * 2.885390082f);     // exp(2a)
        }
  }

  // Block weight: sign(N/R half); off-diag x2 (symmetry). Row 8192
  // boundary == block 64, so sign is block-uniform.
  float wgt = ((bm < NB / 2) == (bn < NB / 2)) ? 1.f : -1.f;
  if (bm != bn) wgt *= 2.f;

  #pragma unroll
  for (int off = 32; off; off >>= 1) partial += __shfl_down(partial, off);
  if (lane == 0) partials[blockIdx.x * 4 + wid] = partial * wgt;
}

// ---------------------------------------------------------------------------
// Pass 3: reduce the 33k per-wave partials, sqrt, store the scalar.
// ---------------------------------------------------------------------------
__global__ __launch_bounds__(1024) void finalize_kernel(
    const float* __restrict__ partials, float* __restrict__ out) {
  float s = 0.f;
  for (int i = threadIdx.x; i < NPART; i += 1024) s += partials[i];
  #pragma unroll
  for (int off = 32; off; off >>= 1) s += __shfl_down(s, off);
  __shared__ float ws[16];
  if ((threadIdx.x & 63) == 0) ws[threadIdx.x >> 6] = s;
  __syncthreads();
  if (threadIdx.x == 0) {
    float tot = 0.f;
    #pragma unroll
    for (int i = 0; i < 16; ++i) tot += ws[i];
    float mmd = tot / ((float)HALF * (float)HALF);
    out[0] = sqrtf(fmaxf(mmd, 0.f));
  }
}

extern "C" void kernel_launch(void* const* d_in, const int* in_sizes, int n_in,
                              void* d_out, int out_size, void* d_ws, size_t ws_size,
                              hipStream_t stream) {
  const float* Nmat = (const float*)d_in[0];
  const float* Rmat = (const float*)d_in[1];
  float* out = (float*)d_out;

  char* ws = (char*)d_ws;
  unsigned char* Z = (unsigned char*)ws;                     // 16384*256 = 4 MiB
  float* x2       = (float*)(ws + (size_t)MTOT * KDIM);      // 64 KiB
  float* partials = (float*)(ws + (size_t)MTOT * KDIM + MTOT * 4);  // 132 KiB

  convert_kernel<<<MTOT / 4, 256, 0, stream>>>(Nmat, Rmat, (unsigned int*)Z, x2);
  mmd_gemm<<<NBLK, 256, 0, stream>>>(Z, x2, partials);
  finalize_kernel<<<1, 1024, 0, stream>>>(partials, out);
}